// Round 9
// baseline (6504.977 us; speedup 1.0000x reference)
//
#include <hip/hip_runtime.h>
#include <cstddef>
#include <cstdint>

#define BB 64
#define TT 4096
#define HD 64
#define FP 72            // f16 feature stride: 144B = 9 x 16B granules
#define SZ (16 * FP)     // one [16 batches][FP feats] f16 sheet

typedef _Float16 f16;
typedef _Float16 f16x8 __attribute__((ext_vector_type(8)));
typedef _Float16 f16x4 __attribute__((ext_vector_type(4)));
typedef _Float16 f16x2 __attribute__((ext_vector_type(2)));
typedef float f32x4 __attribute__((ext_vector_type(4)));
typedef float v2f __attribute__((ext_vector_type(2)));

// lgkm-only barrier: no vmcnt(0) drain (x-loads ride across; stores are
// fire-and-forget; loads are consumed by the issuing thread).
__device__ __forceinline__ void bar_lgkm() {
    asm volatile("s_waitcnt lgkmcnt(0)\n\ts_barrier" ::: "memory");
}

// ---------------------------------------------------------------------------
// Stats pass 1: 256 blocks = (batch b = blk>>2, T-segment seg = blk&3).
// ---------------------------------------------------------------------------
__global__ __launch_bounds__(256) void stats_part(const float* __restrict__ x,
                                                  float* __restrict__ part) {
    const int b = blockIdx.x >> 2, seg = blockIdx.x & 3;
    const int f = threadIdx.x & 63, grp = threadIdx.x >> 6;
    const float* xb = x + (size_t)b * TT * HD + (size_t)seg * (TT / 4) * HD;
    float s = 0.f, s2 = 0.f;
    for (int t = grp; t < TT / 4; t += 4) {
        float v = xb[t * HD + f];
        s += v;
        s2 = fmaf(v, v, s2);
    }
    __shared__ float ls[4][64];
    __shared__ float ls2[4][64];
    ls[grp][f] = s;
    ls2[grp][f] = s2;
    __syncthreads();
    if (threadIdx.x < 64) {
        float ss = 0.f, ss2 = 0.f;
#pragma unroll
        for (int i = 0; i < 4; ++i) { ss += ls[i][f]; ss2 += ls2[i][f]; }
        part[blockIdx.x * HD + f] = ss;
        part[256 * HD + blockIdx.x * HD + f] = ss2;
    }
}

__global__ __launch_bounds__(64) void stats_fin(const float* __restrict__ part,
                                                float* __restrict__ stats) {
    const int b = blockIdx.x, f = threadIdx.x;
    float s = 0.f, s2 = 0.f;
#pragma unroll
    for (int seg = 0; seg < 4; ++seg) {
        s += part[(b * 4 + seg) * HD + f];
        s2 += part[256 * HD + (b * 4 + seg) * HD + f];
    }
    float mu = s * (1.0f / TT);
    float var = s2 * (1.0f / TT) - mu * mu;
    stats[b * HD + f] = mu;
    stats[BB * HD + b * HD + f] = rsqrtf(var + 1e-5f);
}

// ---------------------------------------------------------------------------
// MFMA recurrent kernel, temporally multiplexed over TWO batch groups.
// 2 blocks x 32 batches (A = first 16, B = next 16), 512 threads (8 waves).
// Interval 2t+g runs group g's step t. Weights (AGPR) and bias shared.
// Waves 0-3: layer1 gates(t); waves 4-7: layer0 gates(t+1). 1 lgkm barrier
// per interval; each group's write->read recurrence spans 2 intervals, so
// the other group's work fills the dependency-latency bubbles.
// ---------------------------------------------------------------------------
__global__ __launch_bounds__(512, 2) void rnn_mfma(
    const float* __restrict__ x,
    const float* __restrict__ Wih0, const float* __restrict__ Whh0,
    const float* __restrict__ bih0, const float* __restrict__ bhh0,
    const float* __restrict__ Wih1, const float* __restrict__ Whh1,
    const float* __restrict__ bih1, const float* __restrict__ bhh1,
    const float* __restrict__ stats,
    float* __restrict__ h1out) {
    const int blk = blockIdx.x;
    const int tid = threadIdx.x;
    const int lane = tid & 63;
    const int wid = tid >> 6;
    const bool L1w = (wid < 4);
    const int wq = wid & 3;
    const int ln15 = lane & 15;
    const int l16 = lane >> 4;

    __shared__ __align__(16) f16 hT0[2][2 * SZ];      // [grp][pp sheet]
    __shared__ __align__(16) f16 hT1[2][8 * SZ];      // [grp][ring slot t&7]
    __shared__ __align__(16) f16 xnb[2][2][8 * SZ];   // [grp][par][tau]

    // ---- weight A-fragments -> AGPRs (verified round-6/8 block) ----
    const float* WA = L1w ? Wih1 : Whh0;   // multiplies h0(t)
    const float* WBm = L1w ? Whh1 : Wih0;  // multiplies h1(t-1) / xn(t+1)
    uint32_t aA[4][2][4], aB[4][2][4];
#pragma unroll
    for (int i = 0; i < 4; ++i) {
        const int row = 64 * i + 16 * wq + ln15;
#pragma unroll
        for (int kt = 0; kt < 2; ++kt) {
            const int fb = 32 * kt + 8 * l16;
            const float4 a0 = *(const float4*)&WA[row * HD + fb];
            const float4 a1 = *(const float4*)&WA[row * HD + fb + 4];
            const float4 b0 = *(const float4*)&WBm[row * HD + fb];
            const float4 b1 = *(const float4*)&WBm[row * HD + fb + 4];
            f16x8 ha = {(f16)a0.x, (f16)a0.y, (f16)a0.z, (f16)a0.w,
                        (f16)a1.x, (f16)a1.y, (f16)a1.z, (f16)a1.w};
            f16x8 hb = {(f16)b0.x, (f16)b0.y, (f16)b0.z, (f16)b0.w,
                        (f16)b1.x, (f16)b1.y, (f16)b1.z, (f16)b1.w};
            uint4 ua = __builtin_bit_cast(uint4, ha);
            uint4 ub = __builtin_bit_cast(uint4, hb);
            asm volatile("v_accvgpr_write_b32 %0, %1" : "=a"(aA[i][kt][0]) : "v"(ua.x));
            asm volatile("v_accvgpr_write_b32 %0, %1" : "=a"(aA[i][kt][1]) : "v"(ua.y));
            asm volatile("v_accvgpr_write_b32 %0, %1" : "=a"(aA[i][kt][2]) : "v"(ua.z));
            asm volatile("v_accvgpr_write_b32 %0, %1" : "=a"(aA[i][kt][3]) : "v"(ua.w));
            asm volatile("v_accvgpr_write_b32 %0, %1" : "=a"(aB[i][kt][0]) : "v"(ub.x));
            asm volatile("v_accvgpr_write_b32 %0, %1" : "=a"(aB[i][kt][1]) : "v"(ub.y));
            asm volatile("v_accvgpr_write_b32 %0, %1" : "=a"(aB[i][kt][2]) : "v"(ub.z));
            asm volatile("v_accvgpr_write_b32 %0, %1" : "=a"(aB[i][kt][3]) : "v"(ub.w));
        }
    }
    f16x8 wAf[4][2], wBf[4][2];
#pragma unroll
    for (int i = 0; i < 4; ++i)
#pragma unroll
        for (int kt = 0; kt < 2; ++kt) {
            uint4 ua = {aA[i][kt][0], aA[i][kt][1], aA[i][kt][2], aA[i][kt][3]};
            uint4 ub = {aB[i][kt][0], aB[i][kt][1], aB[i][kt][2], aB[i][kt][3]};
            wAf[i][kt] = __builtin_bit_cast(f16x8, ua);
            wBf[i][kt] = __builtin_bit_cast(f16x8, ub);
        }

    const float* bi = L1w ? bih1 : bih0;
    const float* bh = L1w ? bhh1 : bhh0;
    f32x4 bias[4];
#pragma unroll
    for (int i = 0; i < 4; ++i)
#pragma unroll
        for (int r = 0; r < 4; ++r) {
            const int row = 64 * i + 16 * wq + 4 * l16 + r;
            bias[i][r] = bi[row] + bh[row];
        }

    // ---- per-group staging constants: thread = (batch sb, feature pair f2) ----
    const int sb = tid >> 5;
    const int f2 = (tid & 31) * 2;
    const size_t gbA = (size_t)blk * 32 + sb;
    const size_t gbB = gbA + 16;
    const v2f aaA = {stats[BB * HD + gbA * HD + f2], stats[BB * HD + gbA * HD + f2 + 1]};
    const v2f aaB = {stats[BB * HD + gbB * HD + f2], stats[BB * HD + gbB * HD + f2 + 1]};
    const v2f bbA = {-stats[gbA * HD + f2] * aaA.x, -stats[gbA * HD + f2 + 1] * aaA.y};
    const v2f bbB = {-stats[gbB * HD + f2] * aaB.x, -stats[gbB * HD + f2 + 1] * aaB.y};
    const float* xrowA = x + gbA * TT * HD;
    const float* xrowB = x + gbB * TT * HD;
    float* orowA = h1out + gbA * TT * HD;
    float* orowB = h1out + gbB * TT * HD;

    // zero hT0 (all sheets) and hT1 rings (slot 7 = h1(-1) = 0)
    for (int i = tid; i < 2 * 2 * SZ / 2; i += 512) ((unsigned*)hT0)[i] = 0u;
    for (int i = tid; i < 2 * 8 * SZ / 2; i += 512) ((unsigned*)hT1)[i] = 0u;

    // prologue: stage chunk 0 (xn 0..7) into par 0, preload xr = x(8..15)
    v2f xrA[8], xrB[8];
#pragma unroll
    for (int tau = 0; tau < 8; ++tau) {
        v2f vA = *(const v2f*)&xrowA[(size_t)tau * HD + f2];
        v2f vB = *(const v2f*)&xrowB[(size_t)tau * HD + f2];
        f16x2 hA, hB;
        hA.x = (f16)fmaf(vA.x, aaA.x, bbA.x); hA.y = (f16)fmaf(vA.y, aaA.y, bbA.y);
        hB.x = (f16)fmaf(vB.x, aaB.x, bbB.x); hB.y = (f16)fmaf(vB.y, aaB.y, bbB.y);
        *(f16x2*)&xnb[0][0][tau * SZ + sb * FP + f2] = hA;
        *(f16x2*)&xnb[1][0][tau * SZ + sb * FP + f2] = hB;
    }
#pragma unroll
    for (int tau = 0; tau < 8; ++tau) {
        xrA[tau] = *(const v2f*)&xrowA[(size_t)(8 + tau) * HD + f2];
        xrB[tau] = *(const v2f*)&xrowB[(size_t)(8 + tau) * HD + f2];
    }

    v2f cstA[2] = {{0.f, 0.f}, {0.f, 0.f}};
    v2f cstB[2] = {{0.f, 0.f}, {0.f, 0.f}};

    auto PHASE = [&](v2f* cstp, const f16* src1, const f16* src2, f16* dest) {
        f16x8 B1k0 = *(const f16x8*)&src1[ln15 * FP + 8 * l16];
        f16x8 B1k1 = *(const f16x8*)&src1[ln15 * FP + 32 + 8 * l16];
        f16x8 B2k0 = *(const f16x8*)&src2[ln15 * FP + 8 * l16];
        f16x8 B2k1 = *(const f16x8*)&src2[ln15 * FP + 32 + 8 * l16];
        f32x4 acc[4];
#pragma unroll
        for (int i = 0; i < 4; ++i) {
            acc[i] = bias[i];
            acc[i] = __builtin_amdgcn_mfma_f32_16x16x32_f16(wAf[i][0], B1k0, acc[i], 0, 0, 0);
            acc[i] = __builtin_amdgcn_mfma_f32_16x16x32_f16(wAf[i][1], B1k1, acc[i], 0, 0, 0);
            acc[i] = __builtin_amdgcn_mfma_f32_16x16x32_f16(wBf[i][0], B2k0, acc[i], 0, 0, 0);
            acc[i] = __builtin_amdgcn_mfma_f32_16x16x32_f16(wBf[i][1], B2k1, acc[i], 0, 0, 0);
        }
        uint32_t hw[2];
#pragma unroll
        for (int rp = 0; rp < 2; ++rp) {
            v2f gi = {acc[0][2 * rp], acc[0][2 * rp + 1]};
            v2f gf = {acc[1][2 * rp], acc[1][2 * rp + 1]};
            v2f gg = {acc[2][2 * rp], acc[2][2 * rp + 1]};
            v2f go = {acc[3][2 * rp], acc[3][2 * rp + 1]};
            v2f ti = gi * -1.44269504f;
            v2f tf = gf * -1.44269504f;
            v2f tg = gg * 2.88539008f;
            v2f to = go * -1.44269504f;
            v2f emi = {__builtin_amdgcn_exp2f(ti.x), __builtin_amdgcn_exp2f(ti.y)};
            v2f emf = {__builtin_amdgcn_exp2f(tf.x), __builtin_amdgcn_exp2f(tf.y)};
            v2f eg2 = {__builtin_amdgcn_exp2f(tg.x), __builtin_amdgcn_exp2f(tg.y)};
            v2f emo = {__builtin_amdgcn_exp2f(to.x), __builtin_amdgcn_exp2f(to.y)};
            v2f dig = (emi + 1.0f) * (eg2 + 1.0f);
            v2f rig = {__builtin_amdgcn_rcpf(dig.x), __builtin_amdgcn_rcpf(dig.y)};
            v2f ig = (eg2 - 1.0f) * rig;
            v2f dnf = emf + 1.0f;
            v2f fg2 = {__builtin_amdgcn_rcpf(dnf.x), __builtin_amdgcn_rcpf(dnf.y)};
            v2f c = fg2 * cstp[rp] + ig;
            cstp[rp] = c;
            v2f tc2 = c * 2.88539008f;
            v2f ec2 = {__builtin_amdgcn_exp2f(tc2.x), __builtin_amdgcn_exp2f(tc2.y)};
            v2f dno = (emo + 1.0f) * (ec2 + 1.0f);
            v2f rno = {__builtin_amdgcn_rcpf(dno.x), __builtin_amdgcn_rcpf(dno.y)};
            v2f h = (ec2 - 1.0f) * rno;
            f16x2 hh;
            hh.x = (f16)h.x;
            hh.y = (f16)h.y;
            hw[rp] = __builtin_bit_cast(uint32_t, hh);
        }
        uint2 hu = {hw[0], hw[1]};
        *(f16x4*)&dest[ln15 * FP + 16 * wq + 4 * l16] = __builtin_bit_cast(f16x4, hu);
    };

    // one interval of group g at sub-step n2 (compile-time), base step tb
    auto STEP = [&](int n2, int tb, v2f* cstg, v2f* xrg, f16* hT0g, f16* hT1g,
                    f16* xnbP, f16* xnbQ, v2f aa, v2f bbv,
                    const float* xrowg, float* __restrict__ orowg,
                    bool doLoad, bool doXnb) {
        const f16* src1 = hT0g + (n2 & 1) * SZ;
        const f16* src2 = L1w ? hT1g + ((n2 + 7) & 7) * SZ
                              : (n2 < 7 ? xnbP + (n2 + 1) * SZ : xnbQ);
        f16* dest = L1w ? hT1g + n2 * SZ : hT0g + ((n2 + 1) & 1) * SZ;
        PHASE(cstg, src1, src2, dest);
        const int k = tb + n2;
        // flush h1(k-2)
        if (tb > 0 || n2 >= 2) {
            f16x2 hh = *(const f16x2*)&hT1g[((n2 + 6) & 7) * SZ + sb * FP + f2];
            v2f o = {(float)hh.x, (float)hh.y};
            *(v2f*)&orowg[(size_t)(k - 2) * HD + f2] = o;
        }
        // xnb write for step k+8 from xr[n2] (holds x(k+8))
        if (doXnb) {
            v2f v = xrg[n2];
            f16x2 xh;
            xh.x = (f16)fmaf(v.x, aa.x, bbv.x);
            xh.y = (f16)fmaf(v.y, aa.y, bbv.y);
            *(f16x2*)&xnbQ[n2 * SZ + sb * FP + f2] = xh;
        }
        // issue load of x(k+16)
        if (doLoad) {
            xrg[n2] = *(const v2f*)&xrowg[(size_t)(k + 16) * HD + f2];
        }
    };

    bar_lgkm();
    if (!L1w) {  // layer-0 step 0 for both groups (disjoint LDS, no bar between)
        PHASE(cstA, hT0[0] + SZ, &xnb[0][0][0], hT0[0]);
        PHASE(cstB, hT0[1] + SZ, &xnb[1][0][0], hT0[1]);
    }
    bar_lgkm();

    for (int tb = 0; tb < TT; tb += 8) {
        const int P = (tb >> 3) & 1;
        f16* xnbPA = xnb[0][P];
        f16* xnbQA = xnb[0][P ^ 1];
        f16* xnbPB = xnb[1][P];
        f16* xnbQB = xnb[1][P ^ 1];
        const bool doLoad = (tb < TT - 16);
        const bool doXnb = (tb < TT - 8);
#pragma unroll
        for (int n = 0; n < 16; ++n) {
            const int n2 = n >> 1;
            if ((n & 1) == 0)
                STEP(n2, tb, cstA, xrA, hT0[0], hT1[0], xnbPA, xnbQA,
                     aaA, bbA, xrowA, orowA, doLoad, doXnb);
            else
                STEP(n2, tb, cstB, xrB, hT0[1], hT1[1], xnbPB, xnbQB,
                     aaB, bbB, xrowB, orowB, doLoad, doXnb);
            bar_lgkm();
        }
    }
    // epilogue: flush h1(4094), h1(4095) for both groups (slots 6, 7)
    {
        f16x2 a6 = *(const f16x2*)&hT1[0][6 * SZ + sb * FP + f2];
        f16x2 a7 = *(const f16x2*)&hT1[0][7 * SZ + sb * FP + f2];
        v2f o;
        o = (v2f){(float)a6.x, (float)a6.y};
        *(v2f*)&orowA[(size_t)(TT - 2) * HD + f2] = o;
        o = (v2f){(float)a7.x, (float)a7.y};
        *(v2f*)&orowA[(size_t)(TT - 1) * HD + f2] = o;
        f16x2 b6 = *(const f16x2*)&hT1[1][6 * SZ + sb * FP + f2];
        f16x2 b7 = *(const f16x2*)&hT1[1][7 * SZ + sb * FP + f2];
        o = (v2f){(float)b6.x, (float)b6.y};
        *(v2f*)&orowB[(size_t)(TT - 2) * HD + f2] = o;
        o = (v2f){(float)b7.x, (float)b7.y};
        *(v2f*)&orowB[(size_t)(TT - 1) * HD + f2] = o;
    }
}

// ---------------------------------------------------------------------------
// FC + bias + residual, in place on d_out (hout holds h1, rewritten as out).
// ---------------------------------------------------------------------------
__global__ __launch_bounds__(256) void fc_res(float* __restrict__ hout,
                                              const float* __restrict__ x,
                                              const float* __restrict__ Wfc,
                                              const float* __restrict__ bfc) {
    __shared__ __align__(16) float wfc_lds[HD * HD];
    __shared__ float bfc_lds[HD];
    const int tid = threadIdx.x;
#pragma unroll
    for (int i = 0; i < 4; ++i)
        ((float4*)wfc_lds)[tid + 256 * i] = ((const float4*)Wfc)[tid + 256 * i];
    if (tid < HD) bfc_lds[tid] = bfc[tid];

    const size_t row = (size_t)blockIdx.x * 256 + tid;
    float hr[HD];
    {
        const float4* hp = (const float4*)(hout + row * HD);
#pragma unroll
        for (int i = 0; i < 16; ++i) {
            float4 v = hp[i];
            hr[4 * i] = v.x; hr[4 * i + 1] = v.y;
            hr[4 * i + 2] = v.z; hr[4 * i + 3] = v.w;
        }
    }
    __syncthreads();

    const float4* xp = (const float4*)(x + row * HD);
    float4* op = (float4*)(hout + row * HD);
    for (int j4 = 0; j4 < 16; ++j4) {
        float s0 = 0.f, s1 = 0.f, s2 = 0.f, s3 = 0.f;
        const float* w0 = &wfc_lds[(4 * j4 + 0) * HD];
        const float* w1 = &wfc_lds[(4 * j4 + 1) * HD];
        const float* w2 = &wfc_lds[(4 * j4 + 2) * HD];
        const float* w3 = &wfc_lds[(4 * j4 + 3) * HD];
#pragma unroll
        for (int k = 0; k < HD; ++k) {
            s0 = fmaf(w0[k], hr[k], s0);
            s1 = fmaf(w1[k], hr[k], s1);
            s2 = fmaf(w2[k], hr[k], s2);
            s3 = fmaf(w3[k], hr[k], s3);
        }
        float4 xv = xp[j4];
        float4 o;
        o.x = s0 + bfc_lds[4 * j4 + 0] + xv.x;
        o.y = s1 + bfc_lds[4 * j4 + 1] + xv.y;
        o.z = s2 + bfc_lds[4 * j4 + 2] + xv.z;
        o.w = s3 + bfc_lds[4 * j4 + 3] + xv.w;
        op[j4] = o;
    }
}

// ---------------------------------------------------------------------------
extern "C" void kernel_launch(void* const* d_in, const int* in_sizes, int n_in,
                              void* d_out, int out_size, void* d_ws, size_t ws_size,
                              hipStream_t stream) {
    const float* x    = (const float*)d_in[0];
    const float* Wih0 = (const float*)d_in[1];
    const float* Whh0 = (const float*)d_in[2];
    const float* bih0 = (const float*)d_in[3];
    const float* bhh0 = (const float*)d_in[4];
    const float* Wih1 = (const float*)d_in[5];
    const float* Whh1 = (const float*)d_in[6];
    const float* bih1 = (const float*)d_in[7];
    const float* bhh1 = (const float*)d_in[8];
    const float* Wfc  = (const float*)d_in[9];
    const float* bfc  = (const float*)d_in[10];

    float* part  = (float*)d_ws;                 // 2*256*64 floats = 128 KiB
    float* stats = part + 2 * 256 * HD;          // 2*64*64 floats  =  32 KiB
    float* out   = (float*)d_out;

    stats_part<<<256, 256, 0, stream>>>(x, part);
    stats_fin<<<64, 64, 0, stream>>>(part, stats);
    rnn_mfma<<<2, 512, 0, stream>>>(x, Wih0, Whh0, bih0, bhh0,
                                    Wih1, Whh1, bih1, bhh1, stats, out);
    fc_res<<<1024, 256, 0, stream>>>(out, x, Wfc, bfc);
}

// Round 10
// 3477.802 us; speedup vs baseline: 1.8704x; 1.8704x over previous
//
#include <hip/hip_runtime.h>
#include <cstddef>
#include <cstdint>

#define BB 64
#define TT 4096
#define HD 64
#define FP 72  // f16 feature stride: 144B = 9 x 16B granules -> uniform bank spread

typedef _Float16 f16;
typedef _Float16 f16x8 __attribute__((ext_vector_type(8)));
typedef _Float16 f16x4 __attribute__((ext_vector_type(4)));
typedef _Float16 f16x2 __attribute__((ext_vector_type(2)));
typedef float f32x4 __attribute__((ext_vector_type(4)));
typedef float v2f __attribute__((ext_vector_type(2)));

// lgkm-only barrier: no vmcnt(0) drain (loads consumed by issuing thread,
// stores fire-and-forget).
__device__ __forceinline__ void bar_lgkm() {
    asm volatile("s_waitcnt lgkmcnt(0)\n\ts_barrier" ::: "memory");
}

// ---------------------------------------------------------------------------
// Stats pass 1: 256 blocks = (batch b = blk>>2, T-segment seg = blk&3).
// ---------------------------------------------------------------------------
__global__ __launch_bounds__(256) void stats_part(const float* __restrict__ x,
                                                  float* __restrict__ part) {
    const int b = blockIdx.x >> 2, seg = blockIdx.x & 3;
    const int f = threadIdx.x & 63, grp = threadIdx.x >> 6;
    const float* xb = x + (size_t)b * TT * HD + (size_t)seg * (TT / 4) * HD;
    float s = 0.f, s2 = 0.f;
    for (int t = grp; t < TT / 4; t += 4) {
        float v = xb[t * HD + f];
        s += v;
        s2 = fmaf(v, v, s2);
    }
    __shared__ float ls[4][64];
    __shared__ float ls2[4][64];
    ls[grp][f] = s;
    ls2[grp][f] = s2;
    __syncthreads();
    if (threadIdx.x < 64) {
        float ss = 0.f, ss2 = 0.f;
#pragma unroll
        for (int i = 0; i < 4; ++i) { ss += ls[i][f]; ss2 += ls2[i][f]; }
        part[blockIdx.x * HD + f] = ss;
        part[256 * HD + blockIdx.x * HD + f] = ss2;
    }
}

__global__ __launch_bounds__(64) void stats_fin(const float* __restrict__ part,
                                                float* __restrict__ stats) {
    const int b = blockIdx.x, f = threadIdx.x;
    float s = 0.f, s2 = 0.f;
#pragma unroll
    for (int seg = 0; seg < 4; ++seg) {
        s += part[(b * 4 + seg) * HD + f];
        s2 += part[256 * HD + (b * 4 + seg) * HD + f];
    }
    float mu = s * (1.0f / TT);
    float var = s2 * (1.0f / TT) - mu * mu;
    stats[b * HD + f] = mu;
    stats[BB * HD + b * HD + f] = rsqrtf(var + 1e-5f);
}

// ---------------------------------------------------------------------------
// MFMA recurrent kernel, 4 waves/block (both layers fused per wave).
// 4 blocks x 16 batches, 256 threads. Wave wq computes, per interval:
//   L1(t):  gates for rows {64i+16wq}, i=0..3, from h0(t) & h1(t-1)
//   L0(t+1): gates for the same row set,      from h0(t) & xn(t+1)
// Two independent MFMA/activation chains per wave fill each other's latency
// bubbles (1 wave/SIMD). Both layers share the h0 B-fragments (6 ds_reads
// instead of 8). One lgkm barrier per step. AGPR-pinned weights (2 layers).
// ---------------------------------------------------------------------------
__global__ __launch_bounds__(256, 1) void rnn_mfma(
    const float* __restrict__ x,
    const float* __restrict__ Wih0, const float* __restrict__ Whh0,
    const float* __restrict__ bih0, const float* __restrict__ bhh0,
    const float* __restrict__ Wih1, const float* __restrict__ Whh1,
    const float* __restrict__ bih1, const float* __restrict__ bhh1,
    const float* __restrict__ stats,
    float* __restrict__ h1out) {
    const int blk = blockIdx.x;
    const int tid = threadIdx.x;
    const int lane = tid & 63;
    const int wq = tid >> 6;        // wave 0..3
    const int ln15 = lane & 15;
    const int l16 = lane >> 4;

    __shared__ __align__(16) f16 hT0[2][16 * FP];     // h0 ping-pong [batch][feat]
    __shared__ __align__(16) f16 hT1[16][16 * FP];    // h1 ring (slot = t&15)
    __shared__ __align__(16) f16 xnb[2][8][16 * FP];  // xn chunk dbuf

    // ---- weight A-fragments -> AGPRs, BOTH layers ----
    // L1: wA1 = Wih1 (x h0), wB1 = Whh1 (x h1prev)
    // L0: wA0 = Whh0 (x h0), wB0 = Wih0 (x xn)
    uint32_t ag[2][2][4][2][4];  // [layer][A/B][i][kt][dword]
#pragma unroll
    for (int L = 0; L < 2; ++L) {
        const float* WA = L ? Wih1 : Whh0;
        const float* WBm = L ? Whh1 : Wih0;
#pragma unroll
        for (int i = 0; i < 4; ++i) {
            const int row = 64 * i + 16 * wq + ln15;
#pragma unroll
            for (int kt = 0; kt < 2; ++kt) {
                const int fb = 32 * kt + 8 * l16;
                const float4 a0 = *(const float4*)&WA[row * HD + fb];
                const float4 a1 = *(const float4*)&WA[row * HD + fb + 4];
                const float4 b0 = *(const float4*)&WBm[row * HD + fb];
                const float4 b1 = *(const float4*)&WBm[row * HD + fb + 4];
                f16x8 ha = {(f16)a0.x, (f16)a0.y, (f16)a0.z, (f16)a0.w,
                            (f16)a1.x, (f16)a1.y, (f16)a1.z, (f16)a1.w};
                f16x8 hb = {(f16)b0.x, (f16)b0.y, (f16)b0.z, (f16)b0.w,
                            (f16)b1.x, (f16)b1.y, (f16)b1.z, (f16)b1.w};
                uint4 ua = __builtin_bit_cast(uint4, ha);
                uint4 ub = __builtin_bit_cast(uint4, hb);
                asm volatile("v_accvgpr_write_b32 %0, %1" : "=a"(ag[L][0][i][kt][0]) : "v"(ua.x));
                asm volatile("v_accvgpr_write_b32 %0, %1" : "=a"(ag[L][0][i][kt][1]) : "v"(ua.y));
                asm volatile("v_accvgpr_write_b32 %0, %1" : "=a"(ag[L][0][i][kt][2]) : "v"(ua.z));
                asm volatile("v_accvgpr_write_b32 %0, %1" : "=a"(ag[L][0][i][kt][3]) : "v"(ua.w));
                asm volatile("v_accvgpr_write_b32 %0, %1" : "=a"(ag[L][1][i][kt][0]) : "v"(ub.x));
                asm volatile("v_accvgpr_write_b32 %0, %1" : "=a"(ag[L][1][i][kt][1]) : "v"(ub.y));
                asm volatile("v_accvgpr_write_b32 %0, %1" : "=a"(ag[L][1][i][kt][2]) : "v"(ub.z));
                asm volatile("v_accvgpr_write_b32 %0, %1" : "=a"(ag[L][1][i][kt][3]) : "v"(ub.w));
            }
        }
    }
    f16x8 wA1[4][2], wB1[4][2], wA0[4][2], wB0[4][2];
#pragma unroll
    for (int i = 0; i < 4; ++i)
#pragma unroll
        for (int kt = 0; kt < 2; ++kt) {
            uint4 u10 = {ag[1][0][i][kt][0], ag[1][0][i][kt][1], ag[1][0][i][kt][2], ag[1][0][i][kt][3]};
            uint4 u11 = {ag[1][1][i][kt][0], ag[1][1][i][kt][1], ag[1][1][i][kt][2], ag[1][1][i][kt][3]};
            uint4 u00 = {ag[0][0][i][kt][0], ag[0][0][i][kt][1], ag[0][0][i][kt][2], ag[0][0][i][kt][3]};
            uint4 u01 = {ag[0][1][i][kt][0], ag[0][1][i][kt][1], ag[0][1][i][kt][2], ag[0][1][i][kt][3]};
            wA1[i][kt] = __builtin_bit_cast(f16x8, u10);
            wB1[i][kt] = __builtin_bit_cast(f16x8, u11);
            wA0[i][kt] = __builtin_bit_cast(f16x8, u00);
            wB0[i][kt] = __builtin_bit_cast(f16x8, u01);
        }

    // biases, both layers
    f32x4 bias1[4], bias0[4];
#pragma unroll
    for (int i = 0; i < 4; ++i)
#pragma unroll
        for (int r = 0; r < 4; ++r) {
            const int row = 64 * i + 16 * wq + 4 * l16 + r;
            bias1[i][r] = bih1[row] + bhh1[row];
            bias0[i][r] = bih0[row] + bhh0[row];
        }

    // ---- staging constants: thread = (batch sb, feature quad fq) ----
    const int sb = tid >> 4;          // 0..15
    const int fq = (tid & 15) * 4;    // 0,4,..,60
    const size_t gb = (size_t)blk * 16 + sb;
    const float4 mu4 = *(const float4*)&stats[gb * HD + fq];
    const float4 rs4 = *(const float4*)&stats[(size_t)BB * HD + gb * HD + fq];
    const float4 aa4 = rs4;
    const float4 bb4 = {-mu4.x * rs4.x, -mu4.y * rs4.y, -mu4.z * rs4.z, -mu4.w * rs4.w};
    const float* xrow = x + gb * TT * HD;
    float* orow = h1out + gb * TT * HD;

    // zero hT0 (both) and hT1 ring
    for (int i = tid; i < 2 * 16 * FP / 2; i += 256) ((unsigned*)hT0)[i] = 0u;
    for (int i = tid; i < 16 * 16 * FP / 2; i += 256) ((unsigned*)hT1)[i] = 0u;

    // prologue: stage chunk 0 (xn 0..7); preload xr = x(8..15)
    float4 xr[8];
#pragma unroll
    for (int tau = 0; tau < 8; ++tau) {
        float4 v = *(const float4*)&xrow[(size_t)tau * HD + fq];
        f16x4 h4 = {(f16)fmaf(v.x, aa4.x, bb4.x), (f16)fmaf(v.y, aa4.y, bb4.y),
                    (f16)fmaf(v.z, aa4.z, bb4.z), (f16)fmaf(v.w, aa4.w, bb4.w)};
        *(f16x4*)&xnb[0][tau][sb * FP + fq] = h4;
    }
#pragma unroll
    for (int tau = 0; tau < 8; ++tau)
        xr[tau] = *(const float4*)&xrow[(size_t)(8 + tau) * HD + fq];

    v2f cst1[2] = {{0.f, 0.f}, {0.f, 0.f}};
    v2f cst0[2] = {{0.f, 0.f}, {0.f, 0.f}};

    // activation block: acc (+state) -> 4 f16 h-values
    auto ACT = [&](f32x4* acc, v2f* cstp) -> f16x4 {
        uint32_t hw[2];
#pragma unroll
        for (int rp = 0; rp < 2; ++rp) {
            v2f gi = {acc[0][2 * rp], acc[0][2 * rp + 1]};
            v2f gf = {acc[1][2 * rp], acc[1][2 * rp + 1]};
            v2f gg = {acc[2][2 * rp], acc[2][2 * rp + 1]};
            v2f go = {acc[3][2 * rp], acc[3][2 * rp + 1]};
            v2f ti = gi * -1.44269504f;
            v2f tf = gf * -1.44269504f;
            v2f tg = gg * 2.88539008f;
            v2f to = go * -1.44269504f;
            v2f emi = {__builtin_amdgcn_exp2f(ti.x), __builtin_amdgcn_exp2f(ti.y)};
            v2f emf = {__builtin_amdgcn_exp2f(tf.x), __builtin_amdgcn_exp2f(tf.y)};
            v2f eg2 = {__builtin_amdgcn_exp2f(tg.x), __builtin_amdgcn_exp2f(tg.y)};
            v2f emo = {__builtin_amdgcn_exp2f(to.x), __builtin_amdgcn_exp2f(to.y)};
            v2f dig = (emi + 1.0f) * (eg2 + 1.0f);
            v2f rig = {__builtin_amdgcn_rcpf(dig.x), __builtin_amdgcn_rcpf(dig.y)};
            v2f ig = (eg2 - 1.0f) * rig;
            v2f dnf = emf + 1.0f;
            v2f fg2 = {__builtin_amdgcn_rcpf(dnf.x), __builtin_amdgcn_rcpf(dnf.y)};
            v2f c = fg2 * cstp[rp] + ig;
            cstp[rp] = c;
            v2f tc2 = c * 2.88539008f;
            v2f ec2 = {__builtin_amdgcn_exp2f(tc2.x), __builtin_amdgcn_exp2f(tc2.y)};
            v2f dno = (emo + 1.0f) * (ec2 + 1.0f);
            v2f rno = {__builtin_amdgcn_rcpf(dno.x), __builtin_amdgcn_rcpf(dno.y)};
            v2f h = (ec2 - 1.0f) * rno;
            f16x2 hh;
            hh.x = (f16)h.x;
            hh.y = (f16)h.y;
            hw[rp] = __builtin_bit_cast(uint32_t, hh);
        }
        uint2 hu = {hw[0], hw[1]};
        return __builtin_bit_cast(f16x4, hu);
    };

    // fused dual-layer phase for interval k (compile-time slots)
    auto PHASE2 = [&](const f16* s1, const f16* s2, const f16* s3,
                      f16* d1, f16* d0) {
        f16x8 B1k0 = *(const f16x8*)&s1[ln15 * FP + 8 * l16];
        f16x8 B1k1 = *(const f16x8*)&s1[ln15 * FP + 32 + 8 * l16];
        f16x8 B2k0 = *(const f16x8*)&s2[ln15 * FP + 8 * l16];
        f16x8 B2k1 = *(const f16x8*)&s2[ln15 * FP + 32 + 8 * l16];
        f16x8 B3k0 = *(const f16x8*)&s3[ln15 * FP + 8 * l16];
        f16x8 B3k1 = *(const f16x8*)&s3[ln15 * FP + 32 + 8 * l16];
        f32x4 acc1[4], acc0[4];
#pragma unroll
        for (int i = 0; i < 4; ++i) {
            acc1[i] = bias1[i];
            acc1[i] = __builtin_amdgcn_mfma_f32_16x16x32_f16(wA1[i][0], B1k0, acc1[i], 0, 0, 0);
            acc1[i] = __builtin_amdgcn_mfma_f32_16x16x32_f16(wA1[i][1], B1k1, acc1[i], 0, 0, 0);
            acc1[i] = __builtin_amdgcn_mfma_f32_16x16x32_f16(wB1[i][0], B2k0, acc1[i], 0, 0, 0);
            acc1[i] = __builtin_amdgcn_mfma_f32_16x16x32_f16(wB1[i][1], B2k1, acc1[i], 0, 0, 0);
            acc0[i] = bias0[i];
            acc0[i] = __builtin_amdgcn_mfma_f32_16x16x32_f16(wA0[i][0], B1k0, acc0[i], 0, 0, 0);
            acc0[i] = __builtin_amdgcn_mfma_f32_16x16x32_f16(wA0[i][1], B1k1, acc0[i], 0, 0, 0);
            acc0[i] = __builtin_amdgcn_mfma_f32_16x16x32_f16(wB0[i][0], B3k0, acc0[i], 0, 0, 0);
            acc0[i] = __builtin_amdgcn_mfma_f32_16x16x32_f16(wB0[i][1], B3k1, acc0[i], 0, 0, 0);
        }
        f16x4 h1v = ACT(acc1, cst1);
        f16x4 h0v = ACT(acc0, cst0);
        *(f16x4*)&d1[ln15 * FP + 16 * wq + 4 * l16] = h1v;
        *(f16x4*)&d0[ln15 * FP + 16 * wq + 4 * l16] = h0v;
    };

    bar_lgkm();
    // prologue: L0 step 0 only (h0(-1)=0 sheet hT0[1], xn(0)) -> hT0[0]
    {
        const f16* s1 = &hT0[1][0];
        const f16* s3 = &xnb[0][0][0];
        f16x8 B1k0 = *(const f16x8*)&s1[ln15 * FP + 8 * l16];
        f16x8 B1k1 = *(const f16x8*)&s1[ln15 * FP + 32 + 8 * l16];
        f16x8 B3k0 = *(const f16x8*)&s3[ln15 * FP + 8 * l16];
        f16x8 B3k1 = *(const f16x8*)&s3[ln15 * FP + 32 + 8 * l16];
        f32x4 acc0[4];
#pragma unroll
        for (int i = 0; i < 4; ++i) {
            acc0[i] = bias0[i];
            acc0[i] = __builtin_amdgcn_mfma_f32_16x16x32_f16(wA0[i][0], B1k0, acc0[i], 0, 0, 0);
            acc0[i] = __builtin_amdgcn_mfma_f32_16x16x32_f16(wA0[i][1], B1k1, acc0[i], 0, 0, 0);
            acc0[i] = __builtin_amdgcn_mfma_f32_16x16x32_f16(wB0[i][0], B3k0, acc0[i], 0, 0, 0);
            acc0[i] = __builtin_amdgcn_mfma_f32_16x16x32_f16(wB0[i][1], B3k1, acc0[i], 0, 0, 0);
        }
        f16x4 h0v = ACT(acc0, cst0);
        *(f16x4*)&hT0[0][ln15 * FP + 16 * wq + 4 * l16] = h0v;
    }
    bar_lgkm();

    for (int tb = 0; tb < TT; tb += 16) {
#pragma unroll
        for (int k = 0; k < 16; ++k) {
            // ---- fused compute: L1(tb+k), L0(tb+k+1) ----
            {
                const f16* s1 = &hT0[k & 1][0];
                const f16* s2 = &hT1[(k + 15) & 15][0];
                const f16* s3 = &xnb[((k + 1) >> 3) & 1][(k + 1) & 7][0];
                f16* d1 = &hT1[k & 15][0];
                f16* d0 = &hT0[(k + 1) & 1][0];
                PHASE2(s1, s2, s3, d1, d0);
            }
            // ---- even-spread staging ----
            if (tb > 0 || k >= 2) {  // flush h1(t-2)
                f16x4 hh = *(const f16x4*)&hT1[(k + 14) & 15][sb * FP + fq];
                float4 o = {(float)hh[0], (float)hh[1], (float)hh[2], (float)hh[3]};
                *(float4*)&orow[(size_t)(tb + k - 2) * HD + fq] = o;
            }
            {
                const int tc = k & 7;
                if (k < 8 || tb < TT - 16) {  // xnb write for t+8
                    const int bufw = (k < 8) ? 1 : 0;
                    float4 v = xr[tc];
                    f16x4 h4 = {(f16)fmaf(v.x, aa4.x, bb4.x), (f16)fmaf(v.y, aa4.y, bb4.y),
                                (f16)fmaf(v.z, aa4.z, bb4.z), (f16)fmaf(v.w, aa4.w, bb4.w)};
                    *(f16x4*)&xnb[bufw][tc][sb * FP + fq] = h4;
                }
                if (tb < TT - 16) {  // issue load of x(t+16)
                    xr[tc] = *(const float4*)&xrow[(size_t)(tb + 16 + k) * HD + fq];
                }
            }
            bar_lgkm();
        }
    }
    // epilogue: flush h1(4094), h1(4095) (ring slots 14, 15)
    {
        f16x4 h14 = *(const f16x4*)&hT1[14][sb * FP + fq];
        float4 o14 = {(float)h14[0], (float)h14[1], (float)h14[2], (float)h14[3]};
        *(float4*)&orow[(size_t)(TT - 2) * HD + fq] = o14;
        f16x4 h15 = *(const f16x4*)&hT1[15][sb * FP + fq];
        float4 o15 = {(float)h15[0], (float)h15[1], (float)h15[2], (float)h15[3]};
        *(float4*)&orow[(size_t)(TT - 1) * HD + fq] = o15;
    }
}

// ---------------------------------------------------------------------------
// FC + bias + residual, in place on d_out (hout holds h1, rewritten as out).
// ---------------------------------------------------------------------------
__global__ __launch_bounds__(256) void fc_res(float* __restrict__ hout,
                                              const float* __restrict__ x,
                                              const float* __restrict__ Wfc,
                                              const float* __restrict__ bfc) {
    __shared__ __align__(16) float wfc_lds[HD * HD];
    __shared__ float bfc_lds[HD];
    const int tid = threadIdx.x;
#pragma unroll
    for (int i = 0; i < 4; ++i)
        ((float4*)wfc_lds)[tid + 256 * i] = ((const float4*)Wfc)[tid + 256 * i];
    if (tid < HD) bfc_lds[tid] = bfc[tid];

    const size_t row = (size_t)blockIdx.x * 256 + tid;
    float hr[HD];
    {
        const float4* hp = (const float4*)(hout + row * HD);
#pragma unroll
        for (int i = 0; i < 16; ++i) {
            float4 v = hp[i];
            hr[4 * i] = v.x; hr[4 * i + 1] = v.y;
            hr[4 * i + 2] = v.z; hr[4 * i + 3] = v.w;
        }
    }
    __syncthreads();

    const float4* xp = (const float4*)(x + row * HD);
    float4* op = (float4*)(hout + row * HD);
    for (int j4 = 0; j4 < 16; ++j4) {
        float s0 = 0.f, s1 = 0.f, s2 = 0.f, s3 = 0.f;
        const float* w0 = &wfc_lds[(4 * j4 + 0) * HD];
        const float* w1 = &wfc_lds[(4 * j4 + 1) * HD];
        const float* w2 = &wfc_lds[(4 * j4 + 2) * HD];
        const float* w3 = &wfc_lds[(4 * j4 + 3) * HD];
#pragma unroll
        for (int k = 0; k < HD; ++k) {
            s0 = fmaf(w0[k], hr[k], s0);
            s1 = fmaf(w1[k], hr[k], s1);
            s2 = fmaf(w2[k], hr[k], s2);
            s3 = fmaf(w3[k], hr[k], s3);
        }
        float4 xv = xp[j4];
        float4 o;
        o.x = s0 + bfc_lds[4 * j4 + 0] + xv.x;
        o.y = s1 + bfc_lds[4 * j4 + 1] + xv.y;
        o.z = s2 + bfc_lds[4 * j4 + 2] + xv.z;
        o.w = s3 + bfc_lds[4 * j4 + 3] + xv.w;
        op[j4] = o;
    }
}

// ---------------------------------------------------------------------------
extern "C" void kernel_launch(void* const* d_in, const int* in_sizes, int n_in,
                              void* d_out, int out_size, void* d_ws, size_t ws_size,
                              hipStream_t stream) {
    const float* x    = (const float*)d_in[0];
    const float* Wih0 = (const float*)d_in[1];
    const float* Whh0 = (const float*)d_in[2];
    const float* bih0 = (const float*)d_in[3];
    const float* bhh0 = (const float*)d_in[4];
    const float* Wih1 = (const float*)d_in[5];
    const float* Whh1 = (const float*)d_in[6];
    const float* bih1 = (const float*)d_in[7];
    const float* bhh1 = (const float*)d_in[8];
    const float* Wfc  = (const float*)d_in[9];
    const float* bfc  = (const float*)d_in[10];

    float* part  = (float*)d_ws;                 // 2*256*64 floats = 128 KiB
    float* stats = part + 2 * 256 * HD;          // 2*64*64 floats  =  32 KiB
    float* out   = (float*)d_out;

    stats_part<<<256, 256, 0, stream>>>(x, part);
    stats_fin<<<64, 64, 0, stream>>>(part, stats);
    rnn_mfma<<<4, 256, 0, stream>>>(x, Wih0, Whh0, bih0, bhh0,
                                    Wih1, Whh1, bih1, bhh1, stats, out);
    fc_res<<<1024, 256, 0, stream>>>(out, x, Wfc, bfc);
}